// Round 9
// baseline (79.066 us; speedup 1.0000x reference)
//
#include <hip/hip_runtime.h>

#define HW       262144      // 512*512 elements per image plane
#define NBINS    10

// d_ws: 20 cumulative quantities * 32 replica slots (fp32):
//   q in [0,10)  : C[k] = count of (valid & g >= k/10); C[0] == valid total
//   q in [10,20) : S[k] = sum of weighted-log where g >= k/10
#define WS_FLOATS (20 * 32)

typedef __attribute__((address_space(1))) const void as1_cvoid;
typedef __attribute__((address_space(3))) void       as3_void;

__global__ __launch_bounds__(256) void ghm_accum(
    const float* __restrict__ pred, const float* __restrict__ target,
    float* __restrict__ ws)
{
    // [dbuf][stream][wave][lane] : 2*4*4*64*16 B = 32768 B exactly
    __shared__ float4 sbuf[2][4][4][64];

    const int tid  = threadIdx.x;
    const int lane = tid & 63;
    const int wv   = tid >> 6;

    // 1024 blocks * 4 waves = 4096 waves; 128 waves/image;
    // each wave owns 512 contiguous vec4s per stream = 8 chunks of 64.
    const int gw   = blockIdx.x * 4 + wv;
    const int img  = gw >> 7;
    const int base = (gw & 127) * 512;          // vec4 index in image plane

    const float* pp = pred   + (size_t)img * HW;
    const float* th = target + (size_t)img * (3 * HW);

    // per-lane global sources (chunk c adds c*256 floats = 64 vec4s)
    const float* g0 = pp + (size_t)(base + lane) * 4;
    const float* g1 = th + (size_t)(base + lane) * 4;
    const float* g2 = g1 + HW;
    const float* g3 = g2 + HW;

#define STAGE(c, b) do {                                                       \
    __builtin_amdgcn_global_load_lds((as1_cvoid*)(g0 + (c) * 256),             \
        (as3_void*)&sbuf[b][0][wv][0], 16, 0, 0);                              \
    __builtin_amdgcn_global_load_lds((as1_cvoid*)(g1 + (c) * 256),             \
        (as3_void*)&sbuf[b][1][wv][0], 16, 0, 0);                              \
    __builtin_amdgcn_global_load_lds((as1_cvoid*)(g2 + (c) * 256),             \
        (as3_void*)&sbuf[b][2][wv][0], 16, 0, 0);                              \
    __builtin_amdgcn_global_load_lds((as1_cvoid*)(g3 + (c) * 256),             \
        (as3_void*)&sbuf[b][3][wv][0], 16, 0, 0);                              \
} while (0)

    float ck[NBINS], sk[NBINS];
    #pragma unroll
    for (int b = 0; b < NBINS; ++b) { ck[b] = 0.f; sk[b] = 0.f; }

    STAGE(0, 0);                                  // 4 outstanding
    STAGE(1, 1);                                  // 8 outstanding

    #pragma unroll
    for (int c = 0; c < 8; ++c) {
        // wait for chunk c's 4 DMA loads (2-deep pipeline => vmcnt(4))
        if (c < 7) asm volatile("s_waitcnt vmcnt(4)" ::: "memory");
        else       asm volatile("s_waitcnt vmcnt(0)" ::: "memory");

        const int b = c & 1;
        const float4 p4  = sbuf[b][0][wv][lane];
        const float4 hm4 = sbuf[b][1][wv][lane];
        const float4 vl4 = sbuf[b][2][wv][lane];
        const float4 ps4 = sbuf[b][3][wv][lane];

        // reads must complete before this buffer is re-staged
        asm volatile("s_waitcnt lgkmcnt(0)" ::: "memory");
        if (c < 6) STAGE(c + 2, b);

        #pragma unroll
        for (int j = 0; j < 4; ++j) {
            const float p  = (&p4.x)[j];
            const float hm = (&hm4.x)[j];
            const float vl = (&vl4.x)[j];   // 0.0 or 1.0
            const float ps = (&ps4.x)[j];   // 0.0 or 1.0, ps <= vl

            // p in (1e-4, 1-1e-4) => g = |p*vl - ps| < 1 strictly, so
            // in_bin == valid == (vl > 0); count-of-valid == tot.
            const float g  = fabsf(__builtin_fmaf(p, vl, -ps));
            const bool isP = (ps != 0.f);

            const float x  = isP ? p : 1.f - p;
            const float l  = __logf(x);
            const float t  = 1.f - hm;
            const float t2 = t * t;
            const float nw = t2 * t2;                    // (1-hm)^4
            const float lfac = vl * (isP ? l : l * nw);  // masked by valid

            ck[0] += vl;
            sk[0] += lfac;
            #pragma unroll
            for (int bb = 1; bb < NBINS; ++bb) {
                const float edge = (bb == 1) ? 0.1f : (bb == 2) ? 0.2f :
                                   (bb == 3) ? 0.3f : (bb == 4) ? 0.4f :
                                   (bb == 5) ? 0.5f : (bb == 6) ? 0.6f :
                                   (bb == 7) ? 0.7f : (bb == 8) ? 0.8f : 0.9f;
                const float sel = (g >= edge) ? 1.f : 0.f;
                ck[bb] = __builtin_fmaf(sel, vl,   ck[bb]);
                sk[bb] = __builtin_fmaf(sel, lfac, sk[bb]);
            }
        }
    }
#undef STAGE

    // 64-lane butterfly reduce of the 20 register accumulators
    #pragma unroll
    for (int off = 32; off; off >>= 1) {
        #pragma unroll
        for (int b = 0; b < NBINS; ++b) {
            ck[b] += __shfl_xor(ck[b], off);
            sk[b] += __shfl_xor(sk[b], off);
        }
    }

    // lane q (q<20) selects quantity q (compile-time unrolled cndmask chain)
    float myv = 0.f;
    #pragma unroll
    for (int b = 0; b < NBINS; ++b) {
        if (lane == b)         myv = ck[b];
        if (lane == NBINS + b) myv = sk[b];
    }
    if (lane < 20) atomicAdd(&ws[lane * 32 + (gw & 31)], myv);
}

__global__ void ghm_final(const float* __restrict__ ws, float* __restrict__ out)
{
    __shared__ float q[20];
    const int tid = threadIdx.x;
    if (tid < 20) {
        float s = 0.f;
        #pragma unroll
        for (int j = 0; j < 32; ++j) s += ws[tid * 32 + j];
        q[tid] = s;
    }
    __syncthreads();

    if (tid == 0) {
        float tot = q[0];                  // C[0] == valid count
        if (tot < 1.f) tot = 1.f;

        float cnt_b[NBINS], sv[NBINS];
        for (int b = 0; b < NBINS - 1; ++b) {
            cnt_b[b] = q[b]      - q[b + 1];
            sv[b]    = q[10 + b] - q[11 + b];
        }
        cnt_b[NBINS - 1] = q[NBINS - 1];
        sv[NBINS - 1]    = q[19];

        int nne = 0;
        for (int b = 0; b < NBINS; ++b) if (cnt_b[b] > 0.f) nne++;
        const float nn = (nne > 0) ? (float)nne : 1.f;

        float s = 0.f;
        for (int b = 0; b < NBINS; ++b) {
            const float w = (cnt_b[b] > 0.f) ? (tot / fmaxf(cnt_b[b], 1.f)) / nn
                                             : 0.f;
            s += sv[b] * w;
        }
        out[0] = -s / tot;
    }
}

extern "C" void kernel_launch(void* const* d_in, const int* in_sizes, int n_in,
                              void* d_out, int out_size, void* d_ws, size_t ws_size,
                              hipStream_t stream)
{
    const float* pred   = (const float*)d_in[0];
    const float* target = (const float*)d_in[1];
    float*       out    = (float*)d_out;
    float*       ws     = (float*)d_ws;

    hipMemsetAsync(d_ws, 0, WS_FLOATS * sizeof(float), stream);
    ghm_accum<<<1024, 256, 0, stream>>>(pred, target, ws);
    ghm_final<<<1, 64, 0, stream>>>(ws, out);
}

// Round 10
// 47.816 us; speedup vs baseline: 1.6535x; 1.6535x over previous
//
#include <hip/hip_runtime.h>

#define HW       262144      // 512*512 elements per image plane
#define NBINS    10

// d_ws: 20 cumulative quantities * 32 replica slots (fp32):
//   q in [0,10)  : C[k] = count of (valid & g >= k/10); C[0] == valid total
//   q in [10,20) : S[k] = sum of weighted-log where g >= k/10
#define WS_FLOATS (20 * 32)

typedef float f32x4 __attribute__((ext_vector_type(4)));

// Pinned 16-B load: destination registers are OWNED by the asm statement —
// the compiler cannot sink, split, or rematerialize it. saddr base (SGPR
// pair) + per-lane 32-bit byte voffset + 13-bit immediate.
#define LOADQ(dst, voff, base, imm)                                  \
    asm volatile("global_load_dwordx4 %0, %1, %2 offset:" #imm       \
                 : "=v"(dst) : "v"(voff), "s"(base))

__global__ __launch_bounds__(256) void ghm_accum(
    const float* __restrict__ pred, const float* __restrict__ target,
    float* __restrict__ ws)
{
    __shared__ float shred[4][32];

    const int tid  = threadIdx.x;
    const int lane = tid & 63;
    const int wv   = tid >> 6;

    // 2048 blocks: 64 blocks/image, 1024 vec4s per block, 256/wave, 4/lane
    const int img = blockIdx.x >> 6;
    const unsigned vb   = (blockIdx.x & 63) * 1024 + wv * 256 + lane; // vec4 idx
    const unsigned voff = vb * 16;                                    // bytes

    const float* pp = pred   + (size_t)img * HW;        // SGPR base (uniform)
    const float* t0 = target + (size_t)img * (3 * HW);  // hm plane
    const float* t1 = t0 + HW;                          // valid plane
    const float* t2 = t1 + HW;                          // pos plane

    // ---- issue all 16 loads; 256 B/thread pinned in flight ----
    f32x4 P0, P1, P2, P3, H0, H1, H2, H3, V0, V1, V2, V3, S0, S1, S2, S3;
    LOADQ(P0, voff, pp, 0);    LOADQ(P1, voff, pp, 1024);
    LOADQ(P2, voff, pp, 2048); LOADQ(P3, voff, pp, 3072);
    LOADQ(H0, voff, t0, 0);    LOADQ(H1, voff, t0, 1024);
    LOADQ(H2, voff, t0, 2048); LOADQ(H3, voff, t0, 3072);
    LOADQ(V0, voff, t1, 0);    LOADQ(V1, voff, t1, 1024);
    LOADQ(V2, voff, t1, 2048); LOADQ(V3, voff, t1, 3072);
    LOADQ(S0, voff, t2, 0);    LOADQ(S1, voff, t2, 1024);
    LOADQ(S2, voff, t2, 2048); LOADQ(S3, voff, t2, 3072);

    asm volatile("s_waitcnt vmcnt(0)" ::: "memory");
    __builtin_amdgcn_sched_barrier(0);   // nothing crosses the wait (rule #18)

    float ck[NBINS], sk[NBINS];
    #pragma unroll
    for (int b = 0; b < NBINS; ++b) { ck[b] = 0.f; sk[b] = 0.f; }

    const f32x4* Pk[4] = { &P0, &P1, &P2, &P3 };
    const f32x4* Hk[4] = { &H0, &H1, &H2, &H3 };
    const f32x4* Vk[4] = { &V0, &V1, &V2, &V3 };
    const f32x4* Sk[4] = { &S0, &S1, &S2, &S3 };

    #pragma unroll
    for (int k = 0; k < 4; ++k) {
        const f32x4 p4 = *Pk[k], hm4 = *Hk[k], vl4 = *Vk[k], ps4 = *Sk[k];
        #pragma unroll
        for (int j = 0; j < 4; ++j) {
            const float p  = p4[j];
            const float hm = hm4[j];
            const float vl = vl4[j];   // 0.0 or 1.0
            const float ps = ps4[j];   // 0.0 or 1.0, ps <= vl

            // p in (1e-4, 1-1e-4) => g = |p*vl - ps| < 1 strictly, so
            // in_bin == valid == (vl > 0); count-of-valid == tot.
            const float g  = fabsf(__builtin_fmaf(p, vl, -ps));
            const bool isP = (ps != 0.f);

            const float x  = isP ? p : 1.f - p;
            const float l  = __logf(x);
            const float t  = 1.f - hm;
            const float t2 = t * t;
            const float nw = t2 * t2;                    // (1-hm)^4
            const float lfac = vl * (isP ? l : l * nw);  // masked by valid

            ck[0] += vl;
            sk[0] += lfac;
            #pragma unroll
            for (int b = 1; b < NBINS; ++b) {
                const float edge = (b == 1) ? 0.1f : (b == 2) ? 0.2f :
                                   (b == 3) ? 0.3f : (b == 4) ? 0.4f :
                                   (b == 5) ? 0.5f : (b == 6) ? 0.6f :
                                   (b == 7) ? 0.7f : (b == 8) ? 0.8f : 0.9f;
                const float sel = (g >= edge) ? 1.f : 0.f;
                ck[b] = __builtin_fmaf(sel, vl,   ck[b]);
                sk[b] = __builtin_fmaf(sel, lfac, sk[b]);
            }
        }
    }

    // 64-lane butterfly reduce of the 20 register accumulators
    #pragma unroll
    for (int off = 32; off; off >>= 1) {
        #pragma unroll
        for (int b = 0; b < NBINS; ++b) {
            ck[b] += __shfl_xor(ck[b], off);
            sk[b] += __shfl_xor(sk[b], off);
        }
    }

    if (lane == 0) {
        #pragma unroll
        for (int b = 0; b < NBINS; ++b) {
            shred[wv][b]      = ck[b];
            shred[wv][10 + b] = sk[b];
        }
    }
    __syncthreads();

    if (tid < 20) {
        const float s = shred[0][tid] + shred[1][tid] +
                        shred[2][tid] + shred[3][tid];
        atomicAdd(&ws[tid * 32 + (blockIdx.x & 31)], s);
    }
}

__global__ void ghm_final(const float* __restrict__ ws, float* __restrict__ out)
{
    __shared__ float q[20];
    const int tid = threadIdx.x;
    if (tid < 20) {
        float s = 0.f;
        #pragma unroll
        for (int j = 0; j < 32; ++j) s += ws[tid * 32 + j];
        q[tid] = s;
    }
    __syncthreads();

    if (tid == 0) {
        float tot = q[0];                  // C[0] == valid count
        if (tot < 1.f) tot = 1.f;

        float cnt_b[NBINS], sv[NBINS];
        for (int b = 0; b < NBINS - 1; ++b) {
            cnt_b[b] = q[b]      - q[b + 1];
            sv[b]    = q[10 + b] - q[11 + b];
        }
        cnt_b[NBINS - 1] = q[NBINS - 1];
        sv[NBINS - 1]    = q[19];

        int nne = 0;
        for (int b = 0; b < NBINS; ++b) if (cnt_b[b] > 0.f) nne++;
        const float nn = (nne > 0) ? (float)nne : 1.f;

        float s = 0.f;
        for (int b = 0; b < NBINS; ++b) {
            const float w = (cnt_b[b] > 0.f) ? (tot / fmaxf(cnt_b[b], 1.f)) / nn
                                             : 0.f;
            s += sv[b] * w;
        }
        out[0] = -s / tot;
    }
}

extern "C" void kernel_launch(void* const* d_in, const int* in_sizes, int n_in,
                              void* d_out, int out_size, void* d_ws, size_t ws_size,
                              hipStream_t stream)
{
    const float* pred   = (const float*)d_in[0];
    const float* target = (const float*)d_in[1];
    float*       out    = (float*)d_out;
    float*       ws     = (float*)d_ws;

    hipMemsetAsync(d_ws, 0, WS_FLOATS * sizeof(float), stream);
    ghm_accum<<<2048, 256, 0, stream>>>(pred, target, ws);
    ghm_final<<<1, 64, 0, stream>>>(ws, out);
}

// Round 11
// 32.869 us; speedup vs baseline: 2.4055x; 1.4547x over previous
//
#include <hip/hip_runtime.h>

#define HW       262144      // 512*512 elements per image plane
#define NBINS    10
#define NBLOCKS  1024

// d_ws: 20 cumulative quantities * NBLOCKS per-block slots (fp32), plain
// stores (every slot written every call -> no memset needed):
//   ws[q*1024 + block], q in [0,10)  : C[k] = count of (valid & g >= k/10)
//   ws[q*1024 + block], q in [10,20) : S[k] = weighted-log sum where g >= k/10
// C[0] == valid total.

__global__ __launch_bounds__(256) void ghm_accum(
    const float* __restrict__ pred, const float* __restrict__ target,
    float* __restrict__ ws)
{
    __shared__ float shred[4][32];     // per-wave partials

    const int tid  = threadIdx.x;
    const int lane = tid & 63;
    const int wv   = tid >> 6;

    // 1024 blocks: 32 blocks per image, each block owns 2048 consecutive vec4s
    const int img      = blockIdx.x >> 5;
    const int tileBase = (blockIdx.x & 31) * 2048;

    const float* pp = pred   + (size_t)img * HW;
    const float* th = target + (size_t)img * (3 * HW);

    float ck[NBINS], sk[NBINS];
    #pragma unroll
    for (int b = 0; b < NBINS; ++b) { ck[b] = 0.f; sk[b] = 0.f; }

    #pragma unroll 1
    for (int c = 0; c < 2; ++c) {
        const int v0 = tileBase + c * 1024 + tid;

        float4 p4[4], hm4[4], vl4[4], ps4[4];
        #pragma unroll
        for (int k = 0; k < 4; ++k) {
            const int r = (v0 + (k << 8)) << 2;
            p4[k]  = *reinterpret_cast<const float4*>(pp + r);
            hm4[k] = *reinterpret_cast<const float4*>(th + r);
            vl4[k] = *reinterpret_cast<const float4*>(th + HW + r);
            ps4[k] = *reinterpret_cast<const float4*>(th + 2 * HW + r);
        }

        #pragma unroll
        for (int k = 0; k < 4; ++k) {
            #pragma unroll
            for (int j = 0; j < 4; ++j) {
                const float p  = (&p4[k].x)[j];
                const float hm = (&hm4[k].x)[j];
                const float vl = (&vl4[k].x)[j];   // 0.0 or 1.0
                const float ps = (&ps4[k].x)[j];   // 0.0 or 1.0, ps <= vl

                // p in (1e-4, 1-1e-4) => g = |p*vl - ps| < 1 strictly, so
                // in_bin == valid == (vl > 0); count-of-valid == tot.
                const float g  = fabsf(__builtin_fmaf(p, vl, -ps));
                const bool isP = (ps != 0.f);

                const float x  = isP ? p : 1.f - p;
                const float l  = __logf(x);
                const float t  = 1.f - hm;
                const float t2 = t * t;
                const float nw = t2 * t2;                    // (1-hm)^4
                const float lfac = vl * (isP ? l : l * nw);  // masked by valid

                ck[0] += vl;
                sk[0] += lfac;
                #pragma unroll
                for (int b = 1; b < NBINS; ++b) {
                    const float edge = (b == 1) ? 0.1f : (b == 2) ? 0.2f :
                                       (b == 3) ? 0.3f : (b == 4) ? 0.4f :
                                       (b == 5) ? 0.5f : (b == 6) ? 0.6f :
                                       (b == 7) ? 0.7f : (b == 8) ? 0.8f : 0.9f;
                    const float sel = (g >= edge) ? 1.f : 0.f;
                    ck[b] = __builtin_fmaf(sel, vl,   ck[b]);
                    sk[b] = __builtin_fmaf(sel, lfac, sk[b]);
                }
            }
        }
    }

    // 64-lane butterfly reduce of the 20 register accumulators
    #pragma unroll
    for (int off = 32; off; off >>= 1) {
        #pragma unroll
        for (int b = 0; b < NBINS; ++b) {
            ck[b] += __shfl_xor(ck[b], off);
            sk[b] += __shfl_xor(sk[b], off);
        }
    }

    if (lane == 0) {
        #pragma unroll
        for (int b = 0; b < NBINS; ++b) {
            shred[wv][b]      = ck[b];
            shred[wv][10 + b] = sk[b];
        }
    }
    __syncthreads();

    // plain per-block store (no atomic, no memset dependency)
    if (tid < 20) {
        const float s = shred[0][tid] + shred[1][tid] +
                        shred[2][tid] + shred[3][tid];
        ws[tid * NBLOCKS + blockIdx.x] = s;
    }
}

__global__ __launch_bounds__(640) void ghm_final(
    const float* __restrict__ ws, float* __restrict__ out)
{
    __shared__ float qsh[20];
    const int tid = threadIdx.x;
    const int q   = tid >> 5;          // 20 groups of 32 threads
    const int sl  = tid & 31;

    float s = 0.f;
    #pragma unroll
    for (int k = 0; k < 32; ++k)       // coalesced: 32 consecutive per thread
        s += ws[q * NBLOCKS + sl * 32 + k];

    #pragma unroll
    for (int off = 16; off; off >>= 1) s += __shfl_down(s, off, 32);
    if (sl == 0) qsh[q] = s;
    __syncthreads();

    if (tid == 0) {
        float tot = qsh[0];            // C[0] == valid count
        if (tot < 1.f) tot = 1.f;

        float cnt_b[NBINS], sv[NBINS];
        for (int b = 0; b < NBINS - 1; ++b) {
            cnt_b[b] = qsh[b]      - qsh[b + 1];
            sv[b]    = qsh[10 + b] - qsh[11 + b];
        }
        cnt_b[NBINS - 1] = qsh[NBINS - 1];
        sv[NBINS - 1]    = qsh[19];

        int nne = 0;
        for (int b = 0; b < NBINS; ++b) if (cnt_b[b] > 0.f) nne++;
        const float nn = (nne > 0) ? (float)nne : 1.f;

        float s2 = 0.f;
        for (int b = 0; b < NBINS; ++b) {
            const float w = (cnt_b[b] > 0.f) ? (tot / fmaxf(cnt_b[b], 1.f)) / nn
                                             : 0.f;
            s2 += sv[b] * w;
        }
        out[0] = -s2 / tot;
    }
}

extern "C" void kernel_launch(void* const* d_in, const int* in_sizes, int n_in,
                              void* d_out, int out_size, void* d_ws, size_t ws_size,
                              hipStream_t stream)
{
    const float* pred   = (const float*)d_in[0];
    const float* target = (const float*)d_in[1];
    float*       out    = (float*)d_out;
    float*       ws     = (float*)d_ws;

    ghm_accum<<<NBLOCKS, 256, 0, stream>>>(pred, target, ws);
    ghm_final<<<1, 640, 0, stream>>>(ws, out);
}